// Round 1
// baseline (258.072 us; speedup 1.0000x reference)
//
#include <hip/hip_runtime.h>
#include <hip/hip_bf16.h>
#include <cstdint>
#include <cstddef>

typedef __attribute__((ext_vector_type(8))) short short8;
typedef __attribute__((ext_vector_type(4))) float f32x4;
typedef unsigned short u16;
typedef unsigned int u32;

#define NB 2
#define NS 2048
#define ND 1024
#define NH 16
#define NDK 64

// float -> bf16 round-to-nearest-even
__device__ __forceinline__ u16 f2bf(float f){
  u32 u = __builtin_bit_cast(u32, f);
  u += 0x7fffu + ((u >> 16) & 1u);
  return (u16)(u >> 16);
}

__device__ __forceinline__ short8 mk8(ushort4 lo, ushort4 hi){
  short8 r;
  r[0]=(short)lo.x; r[1]=(short)lo.y; r[2]=(short)lo.z; r[3]=(short)lo.w;
  r[4]=(short)hi.x; r[5]=(short)hi.y; r[6]=(short)hi.z; r[7]=(short)hi.w;
  return r;
}

// ---------------- transpose weights: W (K x N) f32 -> Wt (N x K) bf16 ----------------
__global__ __launch_bounds__(256) void transpose_w_kernel(
    const float* __restrict__ Wq, const float* __restrict__ Wk,
    const float* __restrict__ Wv, const float* __restrict__ Wo,
    u16* __restrict__ Wt)
{
  const int z = blockIdx.z;
  const float* W = (z==0)?Wq:(z==1)?Wk:(z==2)?Wv:Wo;
  u16* dst = Wt + (size_t)z*ND*ND;
  __shared__ float t[32][33];
  const int tx = threadIdx.x, ty = threadIdx.y;   // 32 x 8
  const int n0 = blockIdx.x*32, k0 = blockIdx.y*32;
#pragma unroll
  for (int i=0;i<4;i++) t[ty+i*8][tx] = W[(size_t)(k0+ty+i*8)*ND + n0+tx];
  __syncthreads();
#pragma unroll
  for (int i=0;i<4;i++) dst[(size_t)(n0+ty+i*8)*ND + k0+tx] = f2bf(t[tx][ty+i*8]);
}

// ---------------- GEMM: C(128x128 tiles) = A(M x 1024) * W(1024 x N) + bias ----------------
// MODE 0: A = x (f32), z in {0,1,2} -> Q (scaled by 0.125*log2e), K, Vt(B,H,DK,S)  [bf16 out]
// MODE 1: A = O (bf16) -> d_out = O @ Wo + bo  [f32 out]
template<int MODE>
__global__ __launch_bounds__(256) void gemm_kernel(
    const float* __restrict__ Af32, const u16* __restrict__ Abf,
    const u16* __restrict__ Wtz,
    const float* __restrict__ bias0, const float* __restrict__ bias1, const float* __restrict__ bias2,
    u16* __restrict__ Qout, u16* __restrict__ Kout, u16* __restrict__ Vtout,
    float* __restrict__ Fout)
{
  const int tid  = threadIdx.x;
  const int lane = tid & 63;
  const int wv   = tid >> 6;
  const int a = lane & 15, g = lane >> 4;
  const int wm = wv >> 1, wn = wv & 1;
  const int m0 = blockIdx.y * 128, n0 = blockIdx.x * 128;
  const int z  = (MODE==0) ? (int)blockIdx.z : 0;
  const u16* Wz = Wtz + (size_t)z * (ND*ND);

  __shared__ u16 Al[128][40];   // stride 80B: 16B-aligned rows, conflict-min reads
  __shared__ u16 Bl[128][40];

  f32x4 acc[4][4] = {};

  const int row = tid >> 1;
  const int c0  = (tid & 1) * 16;

#pragma unroll 1
  for (int k0 = 0; k0 < ND; k0 += 32) {
    __syncthreads();
    if constexpr (MODE==0) {
      const float* src = Af32 + (size_t)(m0+row)*ND + k0 + c0;
      float4 v0 = *(const float4*)(src+0);
      float4 v1 = *(const float4*)(src+4);
      float4 v2 = *(const float4*)(src+8);
      float4 v3 = *(const float4*)(src+12);
      ushort4 t0 = make_ushort4(f2bf(v0.x), f2bf(v0.y), f2bf(v0.z), f2bf(v0.w));
      ushort4 t1 = make_ushort4(f2bf(v1.x), f2bf(v1.y), f2bf(v1.z), f2bf(v1.w));
      ushort4 t2 = make_ushort4(f2bf(v2.x), f2bf(v2.y), f2bf(v2.z), f2bf(v2.w));
      ushort4 t3 = make_ushort4(f2bf(v3.x), f2bf(v3.y), f2bf(v3.z), f2bf(v3.w));
      *(ushort4*)&Al[row][c0+0]  = t0;
      *(ushort4*)&Al[row][c0+4]  = t1;
      *(ushort4*)&Al[row][c0+8]  = t2;
      *(ushort4*)&Al[row][c0+12] = t3;
    } else {
      const u16* src = Abf + (size_t)(m0+row)*ND + k0 + c0;
      uint4 u0 = *(const uint4*)(src);
      uint4 u1 = *(const uint4*)(src+8);
      *(uint4*)&Al[row][c0]   = u0;
      *(uint4*)&Al[row][c0+8] = u1;
    }
    {
      const u16* srcw = Wz + (size_t)(n0+row)*ND + k0 + c0;
      uint4 w0 = *(const uint4*)(srcw);
      uint4 w1 = *(const uint4*)(srcw+8);
      *(uint4*)&Bl[row][c0]   = w0;
      *(uint4*)&Bl[row][c0+8] = w1;
    }
    __syncthreads();

    short8 af[4], bfr[4];
#pragma unroll
    for (int mi=0;mi<4;++mi){
      const int rr = wm*64 + mi*16 + a;
      ushort4 lo = *(const ushort4*)&Al[rr][4*g];
      ushort4 hi = *(const ushort4*)&Al[rr][16+4*g];
      af[mi] = mk8(lo,hi);
    }
#pragma unroll
    for (int ni=0;ni<4;++ni){
      const int rr = wn*64 + ni*16 + a;
      ushort4 lo = *(const ushort4*)&Bl[rr][4*g];
      ushort4 hi = *(const ushort4*)&Bl[rr][16+4*g];
      bfr[ni] = mk8(lo,hi);
    }
#pragma unroll
    for (int mi=0;mi<4;++mi)
#pragma unroll
      for (int ni=0;ni<4;++ni)
        acc[mi][ni] = __builtin_amdgcn_mfma_f32_16x16x32_bf16(af[mi], bfr[ni], acc[mi][ni], 0,0,0);
  }

  // epilogue: lane holds D[4g+r][a] per 16x16 tile (HW-verified C/D layout)
#pragma unroll
  for (int mi=0;mi<4;++mi){
#pragma unroll
    for (int ni=0;ni<4;++ni){
      const int n  = n0 + wn*64 + ni*16 + a;
      const int mb = m0 + wm*64 + mi*16 + 4*g;
      if constexpr (MODE==0){
        const float* bp = (z==0)? bias0 : (z==1)? bias1 : bias2;
        const float bias = bp[n];
        const int h = n >> 6, dk = n & 63;
        const int b = mb >> 11, s = mb & 2047;
        if (z==2){
          ushort4 st;
          st.x = f2bf(acc[mi][ni][0]+bias);
          st.y = f2bf(acc[mi][ni][1]+bias);
          st.z = f2bf(acc[mi][ni][2]+bias);
          st.w = f2bf(acc[mi][ni][3]+bias);
          *(ushort4*)&Vtout[(((size_t)b*NH + h)*NDK + dk)*NS + s] = st;  // V transposed
        } else {
          u16* dst = (z==0)? Qout : Kout;
          const float sc = (z==0)? 0.1803368801111601f : 1.0f;  // 0.125*log2(e) folded into Q
#pragma unroll
          for (int r=0;r<4;++r)
            dst[(((size_t)b*NH + h)*NS + (s+r))*NDK + dk] = f2bf((acc[mi][ni][r]+bias)*sc);
        }
      } else {
        const float bias = bias0[n];
#pragma unroll
        for (int r=0;r<4;++r)
          Fout[(size_t)(mb+r)*ND + n] = acc[mi][ni][r] + bias;
      }
    }
  }
}

// ---------------- flash attention (causal), swapped-QK^T, exp2 domain ----------------
// grid: (S/64, B*H); 4 waves x 16 q-rows. Q pre-scaled by 0.125*log2e.
__global__ __launch_bounds__(256) void attn_kernel(
    const u16* __restrict__ Qg, const u16* __restrict__ Kg,
    const u16* __restrict__ Vtg, u16* __restrict__ Og)
{
  const int tid  = threadIdx.x;
  const int lane = tid & 63, wv = tid >> 6;
  const int a = lane & 15, g = lane >> 4;
  const int qb = blockIdx.x;
  const int bh = blockIdx.y;
  const int q0w = qb*64 + wv*16;
  const int q   = q0w + a;

  __shared__ u16 Kl[32][72];   // 144B rows
  __shared__ u16 Vl[64][40];   // 80B rows (V^T tile: [dk][kv])

  // hoist Q fragments (B-operand: n=q=a, k=dk)
  const u16* qptr = Qg + ((size_t)bh*NS + q)*NDK;
  short8 qf[2];
#pragma unroll
  for (int dkh=0; dkh<2; ++dkh){
    ushort4 lo = *(const ushort4*)(qptr + 32*dkh + 4*g);
    ushort4 hi = *(const ushort4*)(qptr + 32*dkh + 16 + 4*g);
    qf[dkh] = mk8(lo,hi);
  }

  float mrun = -1e30f, ls = 0.f;
  f32x4 accO[4] = {};
  const int nt = 2*qb + 2;   // KV tiles of 32

#pragma unroll 1
  for (int t = 0; t < nt; ++t) {
    const int kv0 = t*32;
    __syncthreads();
    { // cooperative staging: K tile [32][64], V^T tile [64][32]
      const int kr = tid >> 3, kc = (tid & 7)*8;
      uint4 kd = *(const uint4*)(Kg + ((size_t)bh*NS + kv0 + kr)*NDK + kc);
      *(uint4*)&Kl[kr][kc] = kd;
      const int vr = tid >> 2, vc = (tid & 3)*8;
      uint4 vd = *(const uint4*)(Vtg + ((size_t)bh*NDK + vr)*NS + kv0 + vc);
      *(uint4*)&Vl[vr][vc] = vd;
    }
    __syncthreads();

    if (kv0 <= q0w + 15) {            // wave-uniform
      // S^T = K * Q^T  -> lane holds S^T[kv0 + kvg*16 + 4g+r][q=a]
      f32x4 sc[2] = {};
#pragma unroll
      for (int kvg=0; kvg<2; ++kvg){
#pragma unroll
        for (int dkh=0; dkh<2; ++dkh){
          ushort4 lo = *(const ushort4*)&Kl[kvg*16 + a][32*dkh + 4*g];
          ushort4 hi = *(const ushort4*)&Kl[kvg*16 + a][32*dkh + 16 + 4*g];
          sc[kvg] = __builtin_amdgcn_mfma_f32_16x16x32_bf16(mk8(lo,hi), qf[dkh], sc[kvg], 0,0,0);
        }
      }
      // causal mask + online softmax (exp2 domain; scale folded into Q)
      float pv[2][4];
      float tmax = -1e30f;
#pragma unroll
      for (int kvg=0; kvg<2; ++kvg)
#pragma unroll
        for (int r=0; r<4; ++r){
          const int kv = kv0 + kvg*16 + 4*g + r;
          const float sv = (kv <= q) ? sc[kvg][r] : -1e30f;
          pv[kvg][r] = sv;
          tmax = fmaxf(tmax, sv);
        }
      tmax = fmaxf(tmax, __shfl_xor(tmax, 16));
      tmax = fmaxf(tmax, __shfl_xor(tmax, 32));
      const float mnew = fmaxf(mrun, tmax);
      const float fsc  = exp2f(mrun - mnew);
      float rsum = 0.f;
      short8 pf;
#pragma unroll
      for (int kvg=0; kvg<2; ++kvg)
#pragma unroll
        for (int r=0; r<4; ++r){
          const float p = exp2f(pv[kvg][r] - mnew);
          rsum += p;
          pf[kvg*4 + r] = (short)f2bf(p);
        }
      rsum += __shfl_xor(rsum, 16);
      rsum += __shfl_xor(rsum, 32);
      ls = ls * fsc + rsum;
      mrun = mnew;
      // PV: out^T(dk x q) += V^T * P^T ; P^T feeds B-operand in-register
#pragma unroll
      for (int dkg=0; dkg<4; ++dkg){
        accO[dkg] *= fsc;
        ushort4 lo = *(const ushort4*)&Vl[dkg*16 + a][4*g];
        ushort4 hi = *(const ushort4*)&Vl[dkg*16 + a][16 + 4*g];
        accO[dkg] = __builtin_amdgcn_mfma_f32_16x16x32_bf16(mk8(lo,hi), pf, accO[dkg], 0,0,0);
      }
    }
  }

  // epilogue: lane's acc all belong to q = q0w + a; dk = dkg*16 + 4g + r
  const float inv = 1.0f / ls;
  const int b = bh >> 4, h = bh & 15;
  u16* op = Og + ((size_t)b*NS + q)*ND + h*NDK;
#pragma unroll
  for (int dkg=0; dkg<4; ++dkg){
    ushort4 st;
    st.x = f2bf(accO[dkg][0]*inv);
    st.y = f2bf(accO[dkg][1]*inv);
    st.z = f2bf(accO[dkg][2]*inv);
    st.w = f2bf(accO[dkg][3]*inv);
    *(ushort4*)(op + dkg*16 + 4*g) = st;
  }
}

extern "C" void kernel_launch(void* const* d_in, const int* in_sizes, int n_in,
                              void* d_out, int out_size, void* d_ws, size_t ws_size,
                              hipStream_t stream) {
  (void)in_sizes; (void)n_in; (void)out_size; (void)ws_size;
  const float* x  = (const float*)d_in[0];
  // d_in[1] = mask: causal triu(k=1), hardcoded in attn kernel
  const float* Wq = (const float*)d_in[2];
  const float* bq = (const float*)d_in[3];
  const float* Wk = (const float*)d_in[4];
  const float* bk = (const float*)d_in[5];
  const float* Wv = (const float*)d_in[6];
  const float* bv = (const float*)d_in[7];
  const float* Wo = (const float*)d_in[8];
  const float* bo = (const float*)d_in[9];
  float* out = (float*)d_out;

  // workspace layout (bf16 elems): Wt[4MB elems] | Q | K | Vt | O  (40 MB total)
  u16* Wt  = (u16*)d_ws;
  u16* Qb  = Wt  + (size_t)4*1024*1024;
  u16* Kb  = Qb  + (size_t)4194304;
  u16* Vtb = Kb  + (size_t)4194304;
  u16* Ob  = Vtb + (size_t)4194304;

  transpose_w_kernel<<<dim3(32,32,4), dim3(32,8,1), 0, stream>>>(Wq, Wk, Wv, Wo, Wt);
  gemm_kernel<0><<<dim3(8,32,3), dim3(256), 0, stream>>>(
      x, (const u16*)nullptr, Wt, bq, bk, bv, Qb, Kb, Vtb, (float*)nullptr);
  attn_kernel<<<dim3(32,32,1), dim3(256), 0, stream>>>(Qb, Kb, Vtb, Ob);
  gemm_kernel<1><<<dim3(8,32,1), dim3(256), 0, stream>>>(
      (const float*)nullptr, Ob, Wt + (size_t)3*1024*1024, bo, nullptr, nullptr,
      (u16*)nullptr, (u16*)nullptr, (u16*)nullptr, out);
}